// Round 1
// baseline (131.739 us; speedup 1.0000x reference)
//
#include <hip/hip_runtime.h>

#define D 256
#define NCOEF 5
#define KD 1280   // D * NCOEF
#define NB 8192   // batch rows

typedef __bf16 bf16;
typedef bf16 bf16x8 __attribute__((ext_vector_type(8)));
typedef float f32x4 __attribute__((ext_vector_type(4)));

// ---------------------------------------------------------------------------
// Pack coefs[l][i][o][c] (fp32) -> Wt[l][o][c*256 + i] (bf16).
// GEMM then reads Wt rows K-contiguous ("NT" layout).
// ---------------------------------------------------------------------------
__global__ __launch_bounds__(256) void pack_kernel(const float* __restrict__ coefs,
                                                   bf16* __restrict__ Wt) {
    int t = blockIdx.x * 256 + threadIdx.x;   // 0 .. 2*256*1280-1
    if (t >= 2 * D * KD) return;
    int k = t % KD;
    int o = (t / KD) % D;
    int l = t / (KD * D);
    int c = k / D;
    int i = k % D;
    float v = coefs[(((size_t)l * D + i) * D + o) * NCOEF + c];
    Wt[t] = (bf16)v;
}

// ---------------------------------------------------------------------------
// Per-row LayerNorm + tanh + Jacobi design matrix.
// One wave (64 lanes) per row; lane handles features i = lane + 64*j.
// Output A[row][c*256 + i] bf16 (stores coalesced per c).
// ---------------------------------------------------------------------------
__global__ __launch_bounds__(256) void ew_kernel(const float* __restrict__ h,
                                                 const float* __restrict__ scale,
                                                 const float* __restrict__ bias,
                                                 const float* __restrict__ alpha_p,
                                                 bf16* __restrict__ Aout) {
    int wave = threadIdx.x >> 6;
    int lane = threadIdx.x & 63;
    int row  = (blockIdx.x << 2) + wave;

    const float* hr = h + (size_t)row * D;
    float v[4];
    float s = 0.f, ss = 0.f;
#pragma unroll
    for (int j = 0; j < 4; j++) {
        float x = hr[lane + 64 * j];
        v[j] = x;
        s += x;
        ss += x * x;
    }
#pragma unroll
    for (int off = 32; off > 0; off >>= 1) {
        s  += __shfl_down(s, off);
        ss += __shfl_down(ss, off);
    }
    s  = __shfl(s, 0);
    ss = __shfl(ss, 0);

    float mu   = s * (1.f / D);
    float var  = ss * (1.f / D) - mu * mu;
    float rstd = rsqrtf(var + 1e-6f);
    float a    = tanhf(alpha_p[0]);

    bf16* Ar = Aout + (size_t)row * KD;
#pragma unroll
    for (int j = 0; j < 4; j++) {
        int i = lane + 64 * j;
        float hn = (v[j] - mu) * rstd * scale[i] + bias[i];
        float x  = tanhf(hn);
        float p0 = 1.f;
        float p1 = (a + 1.f) * x;
        Ar[i]       = (bf16)p0;          // c = 0
        Ar[D + i]   = (bf16)p1;          // c = 1
        float pm2 = p0, pm1 = p1;
#pragma unroll
        for (int k = 2; k < NCOEF; k++) {
            float tk  = 2.f * k + 2.f * a;
            float Akc = 2.f * k * (k + 2.f * a) * (tk - 2.f);
            float Bkc = (tk - 1.f) * tk * (tk - 2.f);
            float Ckc = 2.f * (k + a - 1.f) * (k + a - 1.f) * tk;
            float p   = (Bkc * x * pm1 - Ckc * pm2) / Akc;
            Ar[k * D + i] = (bf16)p;     // c = k
            pm2 = pm1;
            pm1 = p;
        }
    }
}

// ---------------------------------------------------------------------------
// GEMM: C[b][o] = (sum_k A[b][k] * Wt[o][k]) / 256
// M=8192, N=256, K=1280. Tiles: BM=BN=64, BK=32. 256 threads = 4 waves,
// each wave computes a 32x32 sub-tile via 2x2 MFMA 16x16x32 bf16.
// ---------------------------------------------------------------------------
__global__ __launch_bounds__(256) void gemm_kernel(const bf16* __restrict__ A,
                                                   const bf16* __restrict__ Wt,
                                                   float* __restrict__ C) {
    __shared__ __align__(16) bf16 sA[64][40];   // BK=32 padded to 40
    __shared__ __align__(16) bf16 sB[64][40];

    const int tid  = threadIdx.x;
    const int lane = tid & 63;
    const int w    = tid >> 6;
    const int wm   = w >> 1;        // 0..1
    const int wn   = w & 1;         // 0..1
    const int row0 = blockIdx.y * 64;
    const int col0 = blockIdx.x * 64;

    const int lr = tid >> 2;        // 0..63  staging row
    const int lk = (tid & 3) * 8;   // 0,8,16,24 staging col

    f32x4 acc[2][2] = {};

    const bf16* Ag = A  + (size_t)(row0 + lr) * KD + lk;
    const bf16* Bg = Wt + (size_t)(col0 + lr) * KD + lk;

    for (int k0 = 0; k0 < KD; k0 += 32) {
        *(uint4*)&sA[lr][lk] = *(const uint4*)(Ag + k0);
        *(uint4*)&sB[lr][lk] = *(const uint4*)(Bg + k0);
        __syncthreads();

        bf16x8 afr[2], bfr[2];
#pragma unroll
        for (int tm = 0; tm < 2; tm++)
            afr[tm] = *(const bf16x8*)&sA[32 * wm + 16 * tm + (lane & 15)][(lane >> 4) * 8];
#pragma unroll
        for (int tn = 0; tn < 2; tn++)
            bfr[tn] = *(const bf16x8*)&sB[32 * wn + 16 * tn + (lane & 15)][(lane >> 4) * 8];

#pragma unroll
        for (int tm = 0; tm < 2; tm++)
#pragma unroll
            for (int tn = 0; tn < 2; tn++)
                acc[tm][tn] = __builtin_amdgcn_mfma_f32_16x16x32_bf16(
                    afr[tm], bfr[tn], acc[tm][tn], 0, 0, 0);
        __syncthreads();
    }

    // Epilogue: C/D layout col = lane&15, row = (lane>>4)*4 + reg
#pragma unroll
    for (int tm = 0; tm < 2; tm++)
#pragma unroll
        for (int tn = 0; tn < 2; tn++)
#pragma unroll
            for (int r = 0; r < 4; r++) {
                int gr = row0 + 32 * wm + 16 * tm + (lane >> 4) * 4 + r;
                int gc = col0 + 32 * wn + 16 * tn + (lane & 15);
                C[(size_t)gr * D + gc] = acc[tm][tn][r] * (1.f / D);
            }
}

// ---------------------------------------------------------------------------
extern "C" void kernel_launch(void* const* d_in, const int* in_sizes, int n_in,
                              void* d_out, int out_size, void* d_ws, size_t ws_size,
                              hipStream_t stream) {
    const float* x        = (const float*)d_in[0];
    const float* coefs    = (const float*)d_in[1];
    const float* alphas   = (const float*)d_in[2];
    const float* ln_scale = (const float*)d_in[3];
    const float* ln_bias  = (const float*)d_in[4];
    float* out = (float*)d_out;

    // Workspace layout (bytes):
    //   Abuf : 8192*1280*2  = 20,971,520   (reused across layers)
    //   Wt   : 2*256*1280*2 =  1,310,720
    // total ~22.3 MB. Layer-1 GEMM output goes into d_out (scratch; fully
    // overwritten by layer-2 GEMM afterwards).
    char* ws = (char*)d_ws;
    bf16* Abuf = (bf16*)ws;
    bf16* Wt   = (bf16*)(ws + (size_t)NB * KD * 2);

    // pack weights (both layers)
    pack_kernel<<<(2 * D * KD + 255) / 256, 256, 0, stream>>>(coefs, Wt);

    // layer 0
    ew_kernel<<<NB / 4, 256, 0, stream>>>(x, ln_scale, ln_bias, alphas, Abuf);
    gemm_kernel<<<dim3(D / 64, NB / 64), 256, 0, stream>>>(Abuf, Wt, out);

    // layer 1 (reads d_out as h, overwrites d_out with final result)
    ew_kernel<<<NB / 4, 256, 0, stream>>>(out, ln_scale + D, ln_bias + D, alphas + 1, Abuf);
    gemm_kernel<<<dim3(D / 64, NB / 64), 256, 0, stream>>>(Abuf, Wt + (size_t)D * KD, out);
}

// Round 2
// 119.362 us; speedup vs baseline: 1.1037x; 1.1037x over previous
//
#include <hip/hip_runtime.h>

#define D 256
#define NCOEF 5
#define KD 1280   // D * NCOEF
#define NB 8192   // batch rows

typedef __bf16 bf16;
typedef bf16 bf16x8 __attribute__((ext_vector_type(8)));
typedef bf16 bf16x4 __attribute__((ext_vector_type(4)));
typedef float f32x4 __attribute__((ext_vector_type(4)));

// async global->LDS, 16B per lane; lds base must be wave-uniform, HW scatters lane i at base + i*16
__device__ __forceinline__ void glds16(const bf16* g, bf16* l) {
    __builtin_amdgcn_global_load_lds((const __attribute__((address_space(1))) void*)g,
                                     (__attribute__((address_space(3))) void*)l, 16, 0, 0);
}

// ---------------------------------------------------------------------------
// Pack coefs[l][i][o][c] (fp32) -> Wt[l][o][c*256 + i] (bf16) via LDS transpose.
// Grid: 2 layers * 5 c-planes * 16 (i,o) 64x64 tiles = 160 blocks.
// ---------------------------------------------------------------------------
__global__ __launch_bounds__(256) void pack_kernel(const float* __restrict__ coefs,
                                                   bf16* __restrict__ Wt) {
    __shared__ float t[64 * 65];   // pad 65 -> bank-free column reads
    int b   = blockIdx.x;
    int l   = b / 80;              // layer
    int rem = b % 80;
    int c   = rem / 16;
    int tl  = rem % 16;
    int i0  = (tl >> 2) * 64, o0 = (tl & 3) * 64;

    for (int j = threadIdx.x; j < 4096; j += 256) {
        int i = j >> 6, o = j & 63;
        t[i * 65 + o] = coefs[(((size_t)(l * 256 + i0 + i)) * 256 + (o0 + o)) * 5 + c];
    }
    __syncthreads();
    for (int j = threadIdx.x; j < 4096; j += 256) {
        int o = j >> 6, i = j & 63;   // i fastest -> coalesced 2B*64 writes
        Wt[((size_t)(l * 256 + o0 + o)) * KD + c * 256 + i0 + i] = (bf16)t[i * 65 + o];
    }
}

// ---------------------------------------------------------------------------
// LayerNorm + tanh + Jacobi design matrix. One wave per row, lane owns i=4l..4l+3.
// float4 load, bf16x4 stores per c-plane.
// ---------------------------------------------------------------------------
__global__ __launch_bounds__(256) void ew_kernel(const float* __restrict__ h,
                                                 const float* __restrict__ scale,
                                                 const float* __restrict__ bias,
                                                 const float* __restrict__ alpha_p,
                                                 bf16* __restrict__ Aout) {
    int wv  = threadIdx.x >> 6;
    int l   = threadIdx.x & 63;
    int row = (blockIdx.x << 2) + wv;

    float4 v = ((const float4*)(h + (size_t)row * D))[l];
    float s  = v.x + v.y + v.z + v.w;
    float ss = v.x * v.x + v.y * v.y + v.z * v.z + v.w * v.w;
#pragma unroll
    for (int off = 32; off > 0; off >>= 1) {
        s  += __shfl_down(s, off);
        ss += __shfl_down(ss, off);
    }
    s  = __shfl(s, 0);
    ss = __shfl(ss, 0);

    float mu   = s * (1.f / D);
    float rstd = rsqrtf(ss * (1.f / D) - mu * mu + 1e-6f);
    float a    = tanhf(alpha_p[0]);

    // Jacobi recurrence constants (k = 2..4), folded to 2 FMA per step
    float rB[3], rC[3];
#pragma unroll
    for (int k = 2; k < NCOEF; k++) {
        float tk  = 2.f * k + 2.f * a;
        float Ak  = 2.f * k * (k + 2.f * a) * (tk - 2.f);
        float iAk = 1.f / Ak;
        rB[k - 2] = (tk - 1.f) * tk * (tk - 2.f) * iAk;
        rC[k - 2] = 2.f * (k + a - 1.f) * (k + a - 1.f) * tk * iAk;
    }

    float4 sc = ((const float4*)scale)[l];
    float4 bi = ((const float4*)bias)[l];
    float hv[4] = {v.x, v.y, v.z, v.w};
    float scv[4] = {sc.x, sc.y, sc.z, sc.w};
    float biv[4] = {bi.x, bi.y, bi.z, bi.w};

    float P[NCOEF][4];
#pragma unroll
    for (int e = 0; e < 4; e++) {
        float x = tanhf((hv[e] - mu) * rstd * scv[e] + biv[e]);
        P[0][e] = 1.f;
        P[1][e] = (a + 1.f) * x;
#pragma unroll
        for (int k = 2; k < NCOEF; k++)
            P[k][e] = rB[k - 2] * x * P[k - 1][e] - rC[k - 2] * P[k - 2][e];
    }

    bf16* Ar = Aout + (size_t)row * KD + 4 * l;
#pragma unroll
    for (int c = 0; c < NCOEF; c++) {
        bf16x4 o;
#pragma unroll
        for (int e = 0; e < 4; e++) o[e] = (bf16)P[c][e];
        *(bf16x4*)(Ar + c * 256) = o;
    }
}

// ---------------------------------------------------------------------------
// GEMM: C[b][o] = (sum_k A[b][k] * Wt[o][k]) / 256.  M=8192, N=256, K=1280.
// Block = 256 thr = 4 waves. Intra-block split-K: wave w owns k-range
// [w*320, w*320+320), 5 iters of BK=64, PRIVATE 16KB staging region ->
// no barriers in the K-loop. global_load_lds width 16, XOR chunk swizzle
// (LDS[r][c8] = G[r][c8 ^ (r&7)]) makes ds_read_b128 fragments 2-way (free).
// Epilogue: dump per-wave 64x64 fp32 tiles to LDS, one barrier, 4-way add.
// Grid 512 blocks -> 2 blocks/CU, 2 waves/SIMD.
// ---------------------------------------------------------------------------
__global__ __launch_bounds__(256, 2) void gemm_kernel(const bf16* __restrict__ A,
                                                      const bf16* __restrict__ Wt,
                                                      float* __restrict__ C) {
    __shared__ __align__(16) bf16 lds[4 * 8192];   // 64 KB, staging then reduction

    const int tid  = threadIdx.x;
    const int l    = tid & 63;
    const int w    = tid >> 6;
    const int row0 = blockIdx.y * 64;
    const int col0 = blockIdx.x * 64;

    bf16* sA = lds + w * 8192;    // 64 rows x 64 k (8 KB)
    bf16* sB = sA + 4096;

    const int kbase  = w * 320;
    const int srow   = l >> 3;            // 0..7 sub-row within an 8-row glds
    const int gchunk = (l & 7) ^ srow;    // swizzled global 8-elem chunk
    const bf16* Ag = A  + (size_t)(row0 + srow) * KD + kbase + gchunk * 8;
    const bf16* Bg = Wt + (size_t)(col0 + srow) * KD + kbase + gchunk * 8;

    f32x4 acc[4][4] = {};

    for (int it = 0; it < 5; ++it) {
        const int ko = it * 64;
#pragma unroll
        for (int t = 0; t < 8; ++t)
            glds16(Ag + ko + t * 8 * KD, sA + t * 512);
#pragma unroll
        for (int t = 0; t < 8; ++t)
            glds16(Bg + ko + t * 8 * KD, sB + t * 512);
        __builtin_amdgcn_s_waitcnt(0x0F70);   // vmcnt(0): glds data landed in LDS

#pragma unroll
        for (int s = 0; s < 2; ++s) {
            bf16x8 af[4], bfr[4];
#pragma unroll
            for (int t = 0; t < 4; ++t) {
                int r  = t * 16 + (l & 15);
                int cc = ((s * 4 + (l >> 4)) ^ (l & 7)) * 8;
                af[t]  = *(const bf16x8*)(sA + r * 64 + cc);
                bfr[t] = *(const bf16x8*)(sB + r * 64 + cc);
            }
#pragma unroll
            for (int tm = 0; tm < 4; tm++)
#pragma unroll
                for (int tn = 0; tn < 4; tn++)
                    acc[tm][tn] = __builtin_amdgcn_mfma_f32_16x16x32_bf16(
                        af[tm], bfr[tn], acc[tm][tn], 0, 0, 0);
        }
    }

    // dump own 64x64 fp32 partial tile into own region (private -> no barrier yet)
    f32x4* dump = (f32x4*)lds + w * 1024;
#pragma unroll
    for (int tm = 0; tm < 4; tm++)
#pragma unroll
        for (int tn = 0; tn < 4; tn++)
            dump[(tm * 4 + tn) * 64 + l] = acc[tm][tn];
    __syncthreads();

    // wave w reduces the tm=w slice across the 4 k-partials and stores it
    f32x4* base = (f32x4*)lds;
#pragma unroll
    for (int tn = 0; tn < 4; tn++) {
        f32x4 v = base[(w * 4 + tn) * 64 + l];
#pragma unroll
        for (int r = 1; r < 4; r++)
            v += base[r * 1024 + (w * 4 + tn) * 64 + l];
        v *= (1.f / 256.f);
        int gr = row0 + w * 16 + (l >> 4) * 4;
        int gc = col0 + tn * 16 + (l & 15);
#pragma unroll
        for (int j = 0; j < 4; j++)
            C[(size_t)(gr + j) * D + gc] = v[j];
    }
}

// ---------------------------------------------------------------------------
extern "C" void kernel_launch(void* const* d_in, const int* in_sizes, int n_in,
                              void* d_out, int out_size, void* d_ws, size_t ws_size,
                              hipStream_t stream) {
    const float* x        = (const float*)d_in[0];
    const float* coefs    = (const float*)d_in[1];
    const float* alphas   = (const float*)d_in[2];
    const float* ln_scale = (const float*)d_in[3];
    const float* ln_bias  = (const float*)d_in[4];
    float* out = (float*)d_out;

    char* ws = (char*)d_ws;
    bf16* Abuf = (bf16*)ws;                                // 8192*1280*2 = 20.97 MB
    bf16* Wt   = (bf16*)(ws + (size_t)NB * KD * 2);        // 2*256*1280*2 = 1.31 MB

    pack_kernel<<<160, 256, 0, stream>>>(coefs, Wt);

    // layer 0
    ew_kernel<<<NB / 4, 256, 0, stream>>>(x, ln_scale, ln_bias, alphas, Abuf);
    gemm_kernel<<<dim3(4, 128), 256, 0, stream>>>(Abuf, Wt, out);

    // layer 1
    ew_kernel<<<NB / 4, 256, 0, stream>>>(out, ln_scale + D, ln_bias + D, alphas + 1, Abuf);
    gemm_kernel<<<dim3(4, 128), 256, 0, stream>>>(Abuf, Wt + (size_t)D * KD, out);
}